// Round 2
// baseline (1207.880 us; speedup 1.0000x reference)
//
#include <hip/hip_runtime.h>
#include <cstdint>
#include <cstddef>

#define B_  4
#define S_  2048
#define D_  1024
#define H_  16
#define HD_ 64
#define M_  (B_ * S_)   // 8192 rows

typedef __bf16 bf16_t;
typedef bf16_t bf16x8 __attribute__((ext_vector_type(8)));
typedef float  floatx4 __attribute__((ext_vector_type(4)));

// ---------------------------------------------------------------------------
// async 16B global -> LDS copy (gfx950). LDS dest must be wave-uniform base +
// lane*16 in issue order (m104/m108 caveat) — our staging layout guarantees it.
// ---------------------------------------------------------------------------
__device__ __forceinline__ void async_copy16(const void* gmem, void* lds) {
  __builtin_amdgcn_global_load_lds(
      (__attribute__((address_space(1))) void*)const_cast<void*>(gmem),
      (__attribute__((address_space(3))) void*)lds,
      16, 0, 0);
}

// ---------------------------------------------------------------------------
// Weight fp32 -> bf16 cast, 4 matrices of 1M elems each, contiguous output.
// ---------------------------------------------------------------------------
__global__ void cast_w_kernel(const float* __restrict__ w0, const float* __restrict__ w1,
                              const float* __restrict__ w2, const float* __restrict__ w3,
                              bf16_t* __restrict__ out) {
  int idx = blockIdx.x * blockDim.x + threadIdx.x;   // 0 .. 4M-1
  const int ONE_M = 1 << 20;
  const float* src = (idx < ONE_M) ? w0 : (idx < 2 * ONE_M) ? w1 : (idx < 3 * ONE_M) ? w2 : w3;
  out[idx] = (bf16_t)src[idx & (ONE_M - 1)];
}

// ---------------------------------------------------------------------------
// Token-shift mix: xr/xk/xv = x*m + shift(x)*(1-m), bf16 outputs.
// ---------------------------------------------------------------------------
__global__ void mix_kernel(const float* __restrict__ x,
                           const float* __restrict__ tmr, const float* __restrict__ tmk,
                           const float* __restrict__ tmv,
                           bf16_t* __restrict__ xr, bf16_t* __restrict__ xk,
                           bf16_t* __restrict__ xv) {
  int idx = blockIdx.x * blockDim.x + threadIdx.x;   // 0 .. 8M-1
  int d = idx & (D_ - 1);
  int t = (idx / D_) & (S_ - 1);
  float xc = x[idx];
  float xp = (t == 0) ? 0.0f : x[idx - D_];
  float mr = tmr[d], mk = tmk[d], mv = tmv[d];
  xr[idx] = (bf16_t)(xc * mr + xp * (1.0f - mr));
  xk[idx] = (bf16_t)(xc * mk + xp * (1.0f - mk));
  xv[idx] = (bf16_t)(xc * mv + xp * (1.0f - mv));
}

// ---------------------------------------------------------------------------
// C[M,N] = A[M,K] * B[N,K]^T, bf16 in / fp32 out. 128x128 tile, BK=32,
// 4 waves each computing 64x64 via 4x4 of 16x16x32 MFMA. m97 structure.
// ---------------------------------------------------------------------------
__global__ __launch_bounds__(256)
void gemm_bt(const bf16_t* __restrict__ A, const bf16_t* __restrict__ Bw,
             float* __restrict__ C, int M, int N, int K) {
  constexpr int BM = 128, BN = 128, BK = 32;
  __shared__ __align__(16) bf16_t As[BM][BK];   // 8 KB
  __shared__ __align__(16) bf16_t Bs[BN][BK];   // 8 KB

  const int tid  = threadIdx.x;
  const int lane = tid & 63;
  const int wave = tid >> 6;
  const int wm   = wave >> 1;      // 0..1
  const int wn   = wave & 1;       // 0..1
  const int l15  = lane & 15;
  const int quad = lane >> 4;      // 0..3

  const int n0 = blockIdx.x * BN;
  const int m0 = blockIdx.y * BM;

  floatx4 acc[4][4] = {};

  const int row0 = tid >> 2;
  const int colb = (tid & 3) * 16;

  const char* Abase = (const char*)(A + (size_t)m0 * K);
  const char* Bbase = (const char*)(Bw + (size_t)n0 * K);
  char* AsB = (char*)&As[0][0];
  char* BsB = (char*)&Bs[0][0];
  const size_t rowpitch = (size_t)K * 2;

  for (int kb = 0; kb < K; kb += BK) {
#pragma unroll
    for (int i = 0; i < 2; ++i) {
      int r = row0 + i * 64;
      int lo = r * 64 + colb;
      async_copy16(Abase + (size_t)r * rowpitch + (size_t)kb * 2 + colb, AsB + lo);
      async_copy16(Bbase + (size_t)r * rowpitch + (size_t)kb * 2 + colb, BsB + lo);
    }
    __syncthreads();   // drains vmcnt(0) then barrier

    bf16x8 afrag[4], bfrag[4];
#pragma unroll
    for (int i = 0; i < 4; ++i) {
      afrag[i] = *(const bf16x8*)&As[wm * 64 + i * 16 + l15][quad * 8];
      bfrag[i] = *(const bf16x8*)&Bs[wn * 64 + i * 16 + l15][quad * 8];
    }
#pragma unroll
    for (int i = 0; i < 4; ++i)
#pragma unroll
      for (int j = 0; j < 4; ++j)
        acc[i][j] = __builtin_amdgcn_mfma_f32_16x16x32_bf16(afrag[i], bfrag[j], acc[i][j], 0, 0, 0);
    __syncthreads();
  }

  // C/D layout (m89-verified): col = lane&15, row = quad*4 + reg
#pragma unroll
  for (int i = 0; i < 4; ++i) {
#pragma unroll
    for (int j = 0; j < 4; ++j) {
      int row = m0 + wm * 64 + i * 16 + quad * 4;
      int col = n0 + wn * 64 + j * 16 + l15;
      float* Cp = C + (size_t)row * N + col;
#pragma unroll
      for (int r = 0; r < 4; ++r)
        Cp[(size_t)r * N] = acc[i][j][r];
    }
  }
}

// ---------------------------------------------------------------------------
// WKV scan: one wave per (b,h), lane = hd. Reference recurrence, exact
// transform: in each (e_hi, e_lo) pair one exponent is 0 so exp(0)==1 —
// compute single exp(-|d|) + select (bit-identical to reference fp32 math).
// Depth-16 register ring prefetch hides the ~900 cy HBM latency (r1: the
// 1-deep prefetch left the loop at ~490 cy/step, pure latency-bound).
// Fuses sigmoid(r)*wkv and GroupNorm sum/sumsq stats.
// ---------------------------------------------------------------------------
#define PF_ 16
__global__ __launch_bounds__(64)
void wkv_scan(const float* __restrict__ rbuf, const float* __restrict__ kbuf,
              const float* __restrict__ vbuf,
              const float* __restrict__ time_decay, const float* __restrict__ time_first,
              float* __restrict__ rwkv, float* __restrict__ stats) {
  const int bh = blockIdx.x;           // 0..63
  const int b = bh / H_, h = bh % H_;
  const int lane = threadIdx.x;        // 0..63 == hd
  const int c = h * HD_ + lane;        // channel within D

  const float w = -__expf(time_decay[c]);
  const float u = time_first[c];

  const size_t base = (size_t)b * S_ * D_ + c;

  float a = 0.0f, bst = -1e38f;
  float sum = 0.0f, sumsq = 0.0f;

  float kq[PF_], vq[PF_], rq[PF_];
#pragma unroll
  for (int i = 0; i < PF_; ++i) {
    size_t idx = base + (size_t)i * D_;
    kq[i] = kbuf[idx]; vq[i] = vbuf[idx]; rq[i] = rbuf[idx];
  }

  size_t widx = base;
  for (int t0 = 0; t0 < S_; t0 += PF_) {
#pragma unroll
    for (int j = 0; j < PF_; ++j) {
      float kt = kq[j], vt = vq[j], rt = rq[j];
      // prefetch step t0+j+PF_ into this slot (wave-uniform condition)
      if (t0 + j + PF_ < S_) {
        size_t nidx = widx + (size_t)PF_ * D_;
        kq[j] = kbuf[nidx]; vq[j] = vbuf[nidx]; rq[j] = rbuf[nidx];
      }

      // out = (e1*a + e2*vt)/(e1+e2+eps); p = max(bst, kt+u)
      float wk = kt + u;
      float d1 = bst - wk;
      float em1 = __expf(-fabsf(d1));
      float e1 = (d1 >= 0.0f) ? 1.0f : em1;
      float e2 = (d1 >= 0.0f) ? em1 : 1.0f;
      float out = __fdividef(e1 * a + e2 * vt, e1 + e2 + 1e-8f);

      // state update; p2 = max(bst+w, kt)
      float ww = bst + w;
      float d2 = ww - kt;
      float em2 = __expf(-fabsf(d2));
      float e1b = (d2 >= 0.0f) ? 1.0f : em2;
      float e2b = (d2 >= 0.0f) ? em2 : 1.0f;
      a   = e1b * a + e2b * vt;
      bst = fmaxf(ww, kt) + __logf(e1b + e2b + 1e-8f);

      float sig = __fdividef(1.0f, 1.0f + __expf(-rt));
      float o = sig * out;
      rwkv[widx] = o;
      sum += o; sumsq += o * o;

      widx += D_;
    }
  }

  // wave-level reduce (64 lanes) for GroupNorm stats over (s, hd)
#pragma unroll
  for (int off = 32; off > 0; off >>= 1) {
    sum   += __shfl_down(sum, off);
    sumsq += __shfl_down(sumsq, off);
  }
  if (lane == 0) {
    const float n = (float)(S_ * HD_);
    float mean = sum / n;
    float var  = sumsq / n - mean * mean;
    stats[2 * bh]     = mean;
    stats[2 * bh + 1] = rsqrtf(var + 1e-5f);
  }
}

// ---------------------------------------------------------------------------
// GroupNorm apply + bf16 cast for the output projection.
// ---------------------------------------------------------------------------
__global__ void norm_cast(const float* __restrict__ rwkv, const float* __restrict__ stats,
                          const float* __restrict__ gamma, const float* __restrict__ beta,
                          bf16_t* __restrict__ normed) {
  int idx = blockIdx.x * blockDim.x + threadIdx.x;   // 0 .. 8M-1
  int d = idx & (D_ - 1);
  int h = d >> 6;
  int b = idx / (S_ * D_);
  int bh = b * H_ + h;
  float mean = stats[2 * bh];
  float rstd = stats[2 * bh + 1];
  float v = (rwkv[idx] - mean) * rstd * gamma[d] + beta[d];
  normed[idx] = (bf16_t)v;
}

// ---------------------------------------------------------------------------
extern "C" void kernel_launch(void* const* d_in, const int* in_sizes, int n_in,
                              void* d_out, int out_size, void* d_ws, size_t ws_size,
                              hipStream_t stream) {
  const float* x     = (const float*)d_in[0];
  const float* tmr   = (const float*)d_in[1];
  const float* tmk   = (const float*)d_in[2];
  const float* tmv   = (const float*)d_in[3];
  const float* Wr    = (const float*)d_in[4];
  const float* Wk    = (const float*)d_in[5];
  const float* Wv    = (const float*)d_in[6];
  const float* Wo    = (const float*)d_in[7];
  const float* td    = (const float*)d_in[8];
  const float* tf    = (const float*)d_in[9];
  const float* gamma = (const float*)d_in[10];
  const float* beta  = (const float*)d_in[11];

  char* ws = (char*)d_ws;
  const size_t MB = 1024 * 1024;
  bf16_t* W_bf   = (bf16_t*)(ws + 0 * MB);     // 4 x 2MB contiguous
  bf16_t* Wr_bf  = (bf16_t*)(ws + 0 * MB);
  bf16_t* Wk_bf  = (bf16_t*)(ws + 2 * MB);
  bf16_t* Wv_bf  = (bf16_t*)(ws + 4 * MB);
  bf16_t* Wo_bf  = (bf16_t*)(ws + 6 * MB);
  bf16_t* xr     = (bf16_t*)(ws + 8 * MB);     // 16MB each
  bf16_t* xk     = (bf16_t*)(ws + 24 * MB);
  bf16_t* xv     = (bf16_t*)(ws + 40 * MB);
  float*  rbuf   = (float*)(ws + 56 * MB);     // 32MB each
  float*  kbuf   = (float*)(ws + 88 * MB);
  float*  vbuf   = (float*)(ws + 120 * MB);
  float*  stats  = (float*)(ws + 152 * MB);    // 64 * 2 floats
  bf16_t* normed = xr;                         // xr dead after GEMM #1

  float* rwkv = (float*)d_out;                 // d_out doubles as fp32 scratch
  float* outp = (float*)d_out;

  cast_w_kernel<<<(4 * 1024 * 1024) / 256, 256, 0, stream>>>(Wr, Wk, Wv, Wo, W_bf);
  mix_kernel<<<(M_ * D_) / 256, 256, 0, stream>>>(x, tmr, tmk, tmv, xr, xk, xv);

  dim3 gg(D_ / 128, M_ / 128);   // (8, 64)
  gemm_bt<<<gg, 256, 0, stream>>>(xr, Wr_bf, rbuf, M_, D_, D_);
  gemm_bt<<<gg, 256, 0, stream>>>(xk, Wk_bf, kbuf, M_, D_, D_);
  gemm_bt<<<gg, 256, 0, stream>>>(xv, Wv_bf, vbuf, M_, D_, D_);

  wkv_scan<<<B_ * H_, 64, 0, stream>>>(rbuf, kbuf, vbuf, td, tf, rwkv, stats);
  norm_cast<<<(M_ * D_) / 256, 256, 0, stream>>>(rwkv, stats, gamma, beta, normed);

  gemm_bt<<<gg, 256, 0, stream>>>(normed, Wo_bf, outp, M_, D_, D_);
}

// Round 4
// 348.167 us; speedup vs baseline: 3.4693x; 3.4693x over previous
//
#include <hip/hip_runtime.h>
#include <cstdint>
#include <cstddef>

#define B_  4
#define S_  2048
#define D_  1024
#define H_  16
#define HD_ 64
#define M_  (B_ * S_)   // 8192 rows

#define CHUNKS_ 64      // parallel chunks per (b,h) sequence
#define CL_     32      // chunk length; CHUNKS_*CL_ == S_

typedef __bf16 bf16_t;
typedef bf16_t bf16x8 __attribute__((ext_vector_type(8)));
typedef float  floatx4 __attribute__((ext_vector_type(4)));

// ---------------------------------------------------------------------------
// async 16B global -> LDS copy (gfx950). LDS dest is wave-uniform base +
// lane*16 (m104/m108); all uses below pass lds = base + lane*16 exactly.
// ---------------------------------------------------------------------------
__device__ __forceinline__ void async_copy16(const void* gmem, void* lds) {
  __builtin_amdgcn_global_load_lds(
      (__attribute__((address_space(1))) void*)const_cast<void*>(gmem),
      (__attribute__((address_space(3))) void*)lds,
      16, 0, 0);
}

// ---------------------------------------------------------------------------
__global__ void cast_w_kernel(const float* __restrict__ w0, const float* __restrict__ w1,
                              const float* __restrict__ w2, const float* __restrict__ w3,
                              bf16_t* __restrict__ out) {
  int idx = blockIdx.x * blockDim.x + threadIdx.x;   // 0 .. 4M-1
  const int ONE_M = 1 << 20;
  const float* src = (idx < ONE_M) ? w0 : (idx < 2 * ONE_M) ? w1 : (idx < 3 * ONE_M) ? w2 : w3;
  out[idx] = (bf16_t)src[idx & (ONE_M - 1)];
}

// ---------------------------------------------------------------------------
__global__ void mix_kernel(const float* __restrict__ x,
                           const float* __restrict__ tmr, const float* __restrict__ tmk,
                           const float* __restrict__ tmv,
                           bf16_t* __restrict__ xr, bf16_t* __restrict__ xk,
                           bf16_t* __restrict__ xv) {
  int idx = blockIdx.x * blockDim.x + threadIdx.x;   // 0 .. 8M-1
  int d = idx & (D_ - 1);
  int t = (idx / D_) & (S_ - 1);
  float xc = x[idx];
  float xp = (t == 0) ? 0.0f : x[idx - D_];
  float mr = tmr[d], mk = tmk[d], mv = tmv[d];
  xr[idx] = (bf16_t)(xc * mr + xp * (1.0f - mr));
  xk[idx] = (bf16_t)(xc * mk + xp * (1.0f - mk));
  xv[idx] = (bf16_t)(xc * mv + xp * (1.0f - mv));
}

// ---------------------------------------------------------------------------
// C[M,N] = A[M,K] * B[N,K]^T, bf16 in / fp32 out. m97 structure (unchanged).
// ---------------------------------------------------------------------------
__global__ __launch_bounds__(256)
void gemm_bt(const bf16_t* __restrict__ A, const bf16_t* __restrict__ Bw,
             float* __restrict__ C, int M, int N, int K) {
  constexpr int BM = 128, BN = 128, BK = 32;
  __shared__ __align__(16) bf16_t As[BM][BK];
  __shared__ __align__(16) bf16_t Bs[BN][BK];

  const int tid  = threadIdx.x;
  const int lane = tid & 63;
  const int wave = tid >> 6;
  const int wm   = wave >> 1;
  const int wn   = wave & 1;
  const int l15  = lane & 15;
  const int quad = lane >> 4;

  const int n0 = blockIdx.x * BN;
  const int m0 = blockIdx.y * BM;

  floatx4 acc[4][4] = {};

  const int row0 = tid >> 2;
  const int colb = (tid & 3) * 16;

  const char* Abase = (const char*)(A + (size_t)m0 * K);
  const char* Bbase = (const char*)(Bw + (size_t)n0 * K);
  char* AsB = (char*)&As[0][0];
  char* BsB = (char*)&Bs[0][0];
  const size_t rowpitch = (size_t)K * 2;

  for (int kb = 0; kb < K; kb += BK) {
#pragma unroll
    for (int i = 0; i < 2; ++i) {
      int r = row0 + i * 64;
      int lo = r * 64 + colb;
      async_copy16(Abase + (size_t)r * rowpitch + (size_t)kb * 2 + colb, AsB + lo);
      async_copy16(Bbase + (size_t)r * rowpitch + (size_t)kb * 2 + colb, BsB + lo);
    }
    __syncthreads();

    bf16x8 afrag[4], bfrag[4];
#pragma unroll
    for (int i = 0; i < 4; ++i) {
      afrag[i] = *(const bf16x8*)&As[wm * 64 + i * 16 + l15][quad * 8];
      bfrag[i] = *(const bf16x8*)&Bs[wn * 64 + i * 16 + l15][quad * 8];
    }
#pragma unroll
    for (int i = 0; i < 4; ++i)
#pragma unroll
      for (int j = 0; j < 4; ++j)
        acc[i][j] = __builtin_amdgcn_mfma_f32_16x16x32_bf16(afrag[i], bfrag[j], acc[i][j], 0, 0, 0);
    __syncthreads();
  }

#pragma unroll
  for (int i = 0; i < 4; ++i) {
#pragma unroll
    for (int j = 0; j < 4; ++j) {
      int row = m0 + wm * 64 + i * 16 + quad * 4;
      int col = n0 + wn * 64 + j * 16 + l15;
      float* Cp = C + (size_t)row * N + col;
#pragma unroll
      for (int r = 0; r < 4; ++r)
        Cp[(size_t)r * N] = acc[i][j][r];
    }
  }
}

// ---------------------------------------------------------------------------
// Pass A: chunk-local b-scan from -inf. G[bh][chunk][lane].
// b_{t+1} = max(b+w, k) + log(e1b + e2b + 1e-8)  — exact reference form.
// ---------------------------------------------------------------------------
__global__ __launch_bounds__(64)
void wkv_chunk_b(const float* __restrict__ kbuf, const float* __restrict__ time_decay,
                 float* __restrict__ G) {
  __shared__ __align__(16) float ks[CL_][64];
  const int blk   = blockIdx.x;
  const int chunk = blk & (CHUNKS_ - 1);
  const int bh    = blk >> 6;
  const int b = bh >> 4, h = bh & 15;
  const int lane = threadIdx.x;
  const int c = h * HD_ + lane;
  const float w = -__expf(time_decay[c]);

  const size_t gbase = ((size_t)b * S_ + (size_t)chunk * CL_) * D_ + h * HD_;
  const char* kg = (const char*)(kbuf + gbase);
  const int rsel = lane >> 4;
  const int csel = (lane & 15) * 16;
#pragma unroll
  for (int i = 0; i < CL_ / 4; ++i) {
    size_t go = (size_t)(i * 4 + rsel) * (D_ * 4) + csel;
    async_copy16(kg + go, (char*)&ks[0][0] + i * 1024 + lane * 16);
  }
  __builtin_amdgcn_s_waitcnt(0);
  __syncthreads();

  float g = -1e38f;
  for (int t = 0; t < CL_; ++t) {
    float kt = ks[t][lane];
    float ww = g + w;
    float d2 = ww - kt;
    float em = __expf(-fabsf(d2));
    float e1b = (d2 >= 0.0f) ? 1.0f : em;
    float e2b = (d2 >= 0.0f) ? em : 1.0f;
    g = fmaxf(ww, kt) + __logf(e1b + e2b + 1e-8f);
  }
  G[(size_t)bh * (CHUNKS_ * 64) + chunk * 64 + lane] = g;
}

// ---------------------------------------------------------------------------
// Merge b across chunks (exact LSE composition): si_b[chunk] = incoming b.
// b' = LSE(b + w*CL, G_chunk). 64 blocks, LDS-staged slab.
// ---------------------------------------------------------------------------
__global__ __launch_bounds__(64)
void wkv_merge_b(const float* __restrict__ G, const float* __restrict__ time_decay,
                 float* __restrict__ si_b) {
  __shared__ __align__(16) float Gs[CHUNKS_][64];
  const int bh = blockIdx.x;
  const int lane = threadIdx.x;
  const int h = bh & 15;
  const int c = h * HD_ + lane;
  const float wL = -__expf(time_decay[c]) * (float)CL_;

  const char* gg = (const char*)(G + (size_t)bh * (CHUNKS_ * 64));
#pragma unroll
  for (int i = 0; i < 16; ++i)
    async_copy16(gg + i * 1024 + lane * 16, (char*)&Gs[0][0] + i * 1024 + lane * 16);
  __builtin_amdgcn_s_waitcnt(0);
  __syncthreads();

  float bst = -1e38f;
  float* so = si_b + (size_t)bh * (CHUNKS_ * 64) + lane;
  for (int ch = 0; ch < CHUNKS_; ++ch) {
    so[ch * 64] = bst;
    float g = Gs[ch][lane];
    float b1 = bst + wL;
    float dd = b1 - g;
    float em = __expf(-fabsf(dd));
    bst = fmaxf(b1, g) + __logf(1.0f + em);
  }
}

// ---------------------------------------------------------------------------
// Pass C: with b_in known, the a-recurrence a' = e1b*a + e2b*v is affine with
// KNOWN coefficients (they depend only on the b-trajectory). Compute the chunk
// transfer a_out = A*a_in + Bv:  A = prod(e1b), Bv = run from a=0.
// ---------------------------------------------------------------------------
__global__ __launch_bounds__(64)
void wkv_chunk_a(const float* __restrict__ kbuf, const float* __restrict__ vbuf,
                 const float* __restrict__ time_decay, const float* __restrict__ si_b,
                 float* __restrict__ cs_A, float* __restrict__ cs_Bv) {
  __shared__ __align__(16) float ks[CL_][64];
  __shared__ __align__(16) float vs[CL_][64];
  const int blk   = blockIdx.x;
  const int chunk = blk & (CHUNKS_ - 1);
  const int bh    = blk >> 6;
  const int b = bh >> 4, h = bh & 15;
  const int lane = threadIdx.x;
  const int c = h * HD_ + lane;
  const float w = -__expf(time_decay[c]);

  const size_t gbase = ((size_t)b * S_ + (size_t)chunk * CL_) * D_ + h * HD_;
  const char* kg = (const char*)(kbuf + gbase);
  const char* vg = (const char*)(vbuf + gbase);
  const int rsel = lane >> 4;
  const int csel = (lane & 15) * 16;
#pragma unroll
  for (int i = 0; i < CL_ / 4; ++i) {
    size_t go = (size_t)(i * 4 + rsel) * (D_ * 4) + csel;
    async_copy16(kg + go, (char*)&ks[0][0] + i * 1024 + lane * 16);
    async_copy16(vg + go, (char*)&vs[0][0] + i * 1024 + lane * 16);
  }
  __builtin_amdgcn_s_waitcnt(0);
  __syncthreads();

  const size_t so = (size_t)bh * (CHUNKS_ * 64) + chunk * 64 + lane;
  float bst = si_b[so];
  float a = 0.0f, Ap = 1.0f;
  for (int t = 0; t < CL_; ++t) {
    float kt = ks[t][lane], vt = vs[t][lane];
    float ww = bst + w;
    float d2 = ww - kt;
    float em = __expf(-fabsf(d2));
    float e1b = (d2 >= 0.0f) ? 1.0f : em;
    float e2b = (d2 >= 0.0f) ? em : 1.0f;
    a  = e1b * a + e2b * vt;
    Ap = Ap * e1b;
    bst = fmaxf(ww, kt) + __logf(e1b + e2b + 1e-8f);
  }
  cs_A [so] = Ap;
  cs_Bv[so] = a;
}

// ---------------------------------------------------------------------------
// Merge a across chunks: a_{c+1} = A_c * a_c + Bv_c, a_0 = 0. No transcendentals.
// ---------------------------------------------------------------------------
__global__ __launch_bounds__(64)
void wkv_merge_a(const float* __restrict__ cs_A, const float* __restrict__ cs_Bv,
                 float* __restrict__ si_a) {
  __shared__ __align__(16) float As[CHUNKS_][64];
  __shared__ __align__(16) float Bs[CHUNKS_][64];
  const int bh = blockIdx.x;
  const int lane = threadIdx.x;
  const char* ag = (const char*)(cs_A  + (size_t)bh * (CHUNKS_ * 64));
  const char* bg = (const char*)(cs_Bv + (size_t)bh * (CHUNKS_ * 64));
#pragma unroll
  for (int i = 0; i < 16; ++i) {
    async_copy16(ag + i * 1024 + lane * 16, (char*)&As[0][0] + i * 1024 + lane * 16);
    async_copy16(bg + i * 1024 + lane * 16, (char*)&Bs[0][0] + i * 1024 + lane * 16);
  }
  __builtin_amdgcn_s_waitcnt(0);
  __syncthreads();

  float a = 0.0f;
  float* so = si_a + (size_t)bh * (CHUNKS_ * 64) + lane;
  for (int ch = 0; ch < CHUNKS_; ++ch) {
    so[ch * 64] = a;
    a = As[ch][lane] * a + Bs[ch][lane];
  }
}

// ---------------------------------------------------------------------------
// Pass E: exact reference steps from (a_in, b_in). Fuses sigmoid(r)*wkv and
// GroupNorm partials. exp(0)==1 transform (bit-equivalent to reference).
// ---------------------------------------------------------------------------
__global__ __launch_bounds__(64)
void wkv_final(const float* __restrict__ rbuf, const float* __restrict__ kbuf,
               const float* __restrict__ vbuf,
               const float* __restrict__ time_decay, const float* __restrict__ time_first,
               const float* __restrict__ si_a, const float* __restrict__ si_b,
               float* __restrict__ rwkv, float* __restrict__ psum, float* __restrict__ psq) {
  __shared__ __align__(16) float rs[CL_][64];
  __shared__ __align__(16) float ks[CL_][64];
  __shared__ __align__(16) float vs[CL_][64];
  const int blk   = blockIdx.x;
  const int chunk = blk & (CHUNKS_ - 1);
  const int bh    = blk >> 6;
  const int b = bh >> 4, h = bh & 15;
  const int lane = threadIdx.x;
  const int c = h * HD_ + lane;
  const float w = -__expf(time_decay[c]);
  const float u = time_first[c];

  const size_t gbase = ((size_t)b * S_ + (size_t)chunk * CL_) * D_ + h * HD_;
  const char* rg = (const char*)(rbuf + gbase);
  const char* kg = (const char*)(kbuf + gbase);
  const char* vg = (const char*)(vbuf + gbase);
  const int rsel = lane >> 4;
  const int csel = (lane & 15) * 16;
#pragma unroll
  for (int i = 0; i < CL_ / 4; ++i) {
    size_t go = (size_t)(i * 4 + rsel) * (D_ * 4) + csel;
    async_copy16(rg + go, (char*)&rs[0][0] + i * 1024 + lane * 16);
    async_copy16(kg + go, (char*)&ks[0][0] + i * 1024 + lane * 16);
    async_copy16(vg + go, (char*)&vs[0][0] + i * 1024 + lane * 16);
  }
  __builtin_amdgcn_s_waitcnt(0);
  __syncthreads();

  const size_t so = (size_t)bh * (CHUNKS_ * 64) + chunk * 64 + lane;
  float a = si_a[so], bst = si_b[so];
  float sum = 0.0f, sq = 0.0f;
  size_t widx = gbase + lane;
  for (int t = 0; t < CL_; ++t) {
    float kt = ks[t][lane], vt = vs[t][lane], rt = rs[t][lane];
    float wk = kt + u;
    float d1 = bst - wk;
    float em1 = __expf(-fabsf(d1));
    float e1 = (d1 >= 0.0f) ? 1.0f : em1;
    float e2 = (d1 >= 0.0f) ? em1 : 1.0f;
    float out = __fdividef(e1 * a + e2 * vt, e1 + e2 + 1e-8f);

    float ww = bst + w;
    float d2 = ww - kt;
    float em2 = __expf(-fabsf(d2));
    float e1b = (d2 >= 0.0f) ? 1.0f : em2;
    float e2b = (d2 >= 0.0f) ? em2 : 1.0f;
    a   = e1b * a + e2b * vt;
    bst = fmaxf(ww, kt) + __logf(e1b + e2b + 1e-8f);

    float sig = __fdividef(1.0f, 1.0f + __expf(-rt));
    float o2 = sig * out;
    rwkv[widx] = o2;
    sum += o2; sq += o2 * o2;
    widx += D_;
  }

#pragma unroll
  for (int off = 32; off > 0; off >>= 1) {
    sum += __shfl_down(sum, off);
    sq  += __shfl_down(sq, off);
  }
  if (lane == 0) {
    psum[bh * CHUNKS_ + chunk] = sum;
    psq [bh * CHUNKS_ + chunk] = sq;
  }
}

// ---------------------------------------------------------------------------
__global__ __launch_bounds__(64)
void stats_finalize(const float* __restrict__ psum, const float* __restrict__ psq,
                    float* __restrict__ stats2) {
  const int bh = blockIdx.x;
  const int lane = threadIdx.x;   // CHUNKS_ == 64 == lanes
  float s = psum[bh * CHUNKS_ + lane];
  float q = psq [bh * CHUNKS_ + lane];
#pragma unroll
  for (int off = 32; off > 0; off >>= 1) {
    s += __shfl_down(s, off);
    q += __shfl_down(q, off);
  }
  if (lane == 0) {
    const float n = (float)(S_ * HD_);
    float mean = s / n;
    float var  = q / n - mean * mean;
    stats2[2 * bh]     = mean;
    stats2[2 * bh + 1] = rsqrtf(var + 1e-5f);
  }
}

// ---------------------------------------------------------------------------
__global__ void norm_cast(const float* __restrict__ rwkv, const float* __restrict__ stats2,
                          const float* __restrict__ gamma, const float* __restrict__ beta,
                          bf16_t* __restrict__ normed) {
  int idx = blockIdx.x * blockDim.x + threadIdx.x;   // 0 .. 8M-1
  int d = idx & (D_ - 1);
  int h = d >> 6;
  int b = idx / (S_ * D_);
  int bh = b * H_ + h;
  float mean = stats2[2 * bh];
  float rstd = stats2[2 * bh + 1];
  float v = (rwkv[idx] - mean) * rstd * gamma[d] + beta[d];
  normed[idx] = (bf16_t)v;
}

// ---------------------------------------------------------------------------
extern "C" void kernel_launch(void* const* d_in, const int* in_sizes, int n_in,
                              void* d_out, int out_size, void* d_ws, size_t ws_size,
                              hipStream_t stream) {
  const float* x     = (const float*)d_in[0];
  const float* tmr   = (const float*)d_in[1];
  const float* tmk   = (const float*)d_in[2];
  const float* tmv   = (const float*)d_in[3];
  const float* Wr    = (const float*)d_in[4];
  const float* Wk    = (const float*)d_in[5];
  const float* Wv    = (const float*)d_in[6];
  const float* Wo    = (const float*)d_in[7];
  const float* td    = (const float*)d_in[8];
  const float* tf    = (const float*)d_in[9];
  const float* gamma = (const float*)d_in[10];
  const float* beta  = (const float*)d_in[11];

  char* ws = (char*)d_ws;
  const size_t MB = 1024 * 1024;
  bf16_t* W_bf   = (bf16_t*)(ws + 0 * MB);     // 4 x 2MB contiguous
  bf16_t* Wr_bf  = (bf16_t*)(ws + 0 * MB);
  bf16_t* Wk_bf  = (bf16_t*)(ws + 2 * MB);
  bf16_t* Wv_bf  = (bf16_t*)(ws + 4 * MB);
  bf16_t* Wo_bf  = (bf16_t*)(ws + 6 * MB);
  bf16_t* xr     = (bf16_t*)(ws + 8 * MB);     // 16MB each
  bf16_t* xk     = (bf16_t*)(ws + 24 * MB);
  bf16_t* xv     = (bf16_t*)(ws + 40 * MB);
  float*  rbuf   = (float*)(ws + 56 * MB);     // 32MB each
  float*  kbuf   = (float*)(ws + 88 * MB);
  float*  vbuf   = (float*)(ws + 120 * MB);
  // scan scratch reuses the xk region (dead after GEMM #2). 1MB per array.
  float*  G      = (float*)(ws + 24 * MB);
  float*  cs_A   = (float*)(ws + 25 * MB);
  float*  cs_Bv  = (float*)(ws + 26 * MB);
  float*  si_b   = (float*)(ws + 27 * MB);
  float*  si_a   = (float*)(ws + 28 * MB);
  float*  psum   = (float*)(ws + 29 * MB);     // 16 KB
  float*  psq    = (float*)(ws + 29 * MB + 64 * 1024);
  float*  stats2 = (float*)(ws + 29 * MB + 128 * 1024);
  bf16_t* normed = xr;                         // xr dead after GEMM #1

  float* rwkv = (float*)d_out;                 // d_out doubles as fp32 scratch
  float* outp = (float*)d_out;

  cast_w_kernel<<<(4 * 1024 * 1024) / 256, 256, 0, stream>>>(Wr, Wk, Wv, Wo, W_bf);
  mix_kernel<<<(M_ * D_) / 256, 256, 0, stream>>>(x, tmr, tmk, tmv, xr, xk, xv);

  dim3 gg(D_ / 128, M_ / 128);   // (8, 64)
  gemm_bt<<<gg, 256, 0, stream>>>(xr, Wr_bf, rbuf, M_, D_, D_);
  gemm_bt<<<gg, 256, 0, stream>>>(xk, Wk_bf, kbuf, M_, D_, D_);
  gemm_bt<<<gg, 256, 0, stream>>>(xv, Wv_bf, vbuf, M_, D_, D_);

  wkv_chunk_b<<<B_ * H_ * CHUNKS_, 64, 0, stream>>>(kbuf, td, G);
  wkv_merge_b<<<B_ * H_, 64, 0, stream>>>(G, td, si_b);
  wkv_chunk_a<<<B_ * H_ * CHUNKS_, 64, 0, stream>>>(kbuf, vbuf, td, si_b, cs_A, cs_Bv);
  wkv_merge_a<<<B_ * H_, 64, 0, stream>>>(cs_A, cs_Bv, si_a);
  wkv_final<<<B_ * H_ * CHUNKS_, 64, 0, stream>>>(rbuf, kbuf, vbuf, td, tf,
                                                  si_a, si_b, rwkv, psum, psq);
  stats_finalize<<<B_ * H_, 64, 0, stream>>>(psum, psq, stats2);
  norm_cast<<<(M_ * D_) / 256, 256, 0, stream>>>(rwkv, stats2, gamma, beta, normed);

  gemm_bt<<<gg, 256, 0, stream>>>(normed, Wo_bf, outp, M_, D_, D_);
}